// Round 11
// baseline (141.613 us; speedup 1.0000x reference)
//
#include <hip/hip_runtime.h>

// xDeepFM CIN, MI355X (gfx950) — two-kernel split, R11.
// cin_h: per-batch h-chain + p-vectors.  4 batches/block, wave = (row-half g,
//   batch-pair bp).  W stream per wave is contiguous (2KB/j) and is staged
//   through a WAVE-PRIVATE 4-slot LDS ring via __builtin_amdgcn_global_load_lds
//   (depth-3, manual s_waitcnt vmcnt(4/2/0)) — R8-R10 showed the compiler
//   always sinks register VMEM prefetch (JIT loads -> ~400cyc exposed/j ->
//   35% MfmaUtil); its LDS->MFMA scheduling is near-optimal, so convert the
//   VMEM dependency into an LDS one.  No barriers touched by the ring.
// cin_out: out cols as GEMMs D[o,batch]=W_o@p, N=32 batches; 512 blocks
//   (one M=32 tile each, 4-way K-split), depth-8 rolling prefetch.

typedef _Float16 f16;
typedef _Float16 f16x4 __attribute__((ext_vector_type(4)));
typedef _Float16 f16x8 __attribute__((ext_vector_type(8)));
typedef float f32x4 __attribute__((ext_vector_type(4)));
typedef float f32x16 __attribute__((ext_vector_type(16)));

#define HSTR 72      // h LDS row stride (f16): 144B = 9*16B, b128-aligned
#define PBS  5120    // pW per-batch stride (f16): p0(1024)+p1(2048)+p2(2048)

__device__ __forceinline__ f32x16 zero16() {
    f32x16 v;
#pragma unroll
    for (int i = 0; i < 16; ++i) v[i] = 0.0f;
    return v;
}

// 1KB async copy: lane i moves 16B from (g + lane*8 f16) to ldsbase + lane*16.
__device__ __forceinline__ void cp1k(const f16* g, f16* l) {
    __builtin_amdgcn_global_load_lds(
        (__attribute__((address_space(1))) void*)(unsigned long long)g,
        (__attribute__((address_space(3))) void*)(unsigned int)(unsigned long long)l,
        16, 0, 0);
}
#define WAITV(n) asm volatile("s_waitcnt vmcnt(" #n ")" ::: "memory")

// ---------------- prep: W (fp32 row-major) -> f16 fragment-ordered ----------
// Fragment (mc, kk) = 512 f16; element lane*8+i =
//   W[rbase + mc*32 + (lane&31)][kk*16 + (lane>>5)*8 + i]
// Regions (f16 offsets): H0@0 (W0 r0..63, KK=64) | O0@65536 (W0 r64..127) |
// H1@131072 (W1 r0..63, KK=128) | O1@262144 (W1 r64..127) | O2@393216 (W2 all).
__global__ void __launch_bounds__(256)
prep_frag(const float* __restrict__ W0, const float* __restrict__ W1,
          const float* __restrict__ W2, f16* __restrict__ dst)
{
    int g = (blockIdx.x * 256 + threadIdx.x) * 8;    // grid = 320
    const float* src; int base, KK, rbase;
    if (g < 65536)       { src = W0; base = 0;      KK = 64;  rbase = 0;  }
    else if (g < 131072) { src = W0; base = 65536;  KK = 64;  rbase = 64; }
    else if (g < 262144) { src = W1; base = 131072; KK = 128; rbase = 0;  }
    else if (g < 393216) { src = W1; base = 262144; KK = 128; rbase = 64; }
    else                 { src = W2; base = 393216; KK = 128; rbase = 0;  }
    int local = g - base;
    int frag  = local >> 9;
    int lane  = (local >> 3) & 63;
    int kk    = frag % KK;
    int mc    = frag / KK;
    int row   = rbase + mc * 32 + (lane & 31);
    int col   = kk * 16 + (lane >> 5) * 8;
    int IC    = KK * 16;
    const float* s = src + (size_t)row * IC + col;
    f16x8 o;
#pragma unroll
    for (int i = 0; i < 8; ++i) o[i] = (f16)s[i];
    *(f16x8*)(dst + g) = o;
}

// ---- p-chunk: p rows [jb, jb+32) of one batch -> global (M=32,N=32,K=64) ---
__device__ __forceinline__ void p_chunk(const f16* __restrict__ hrows,
                                        const f16x8 (&pB)[4],
                                        f16* __restrict__ pdst, int t, int q)
{
    f32x16 acc = zero16();
#pragma unroll
    for (int s = 0; s < 4; ++s) {
        f16x8 a = *(const f16x8*)(hrows + t * HSTR + s * 16 + q * 8);
        acc = __builtin_amdgcn_mfma_f32_32x32x16_f16(a, pB[s], acc, 0, 0, 0);
    }
#pragma unroll
    for (int r = 0; r < 16; ++r) {
        int row = (r & 3) + 8 * (r >> 2) + 4 * q;
        pdst[row * 32 + t] = (f16)acc[r];
    }
}

// Stage one j (2KB) into ring slot j&3.
__device__ __forceinline__ void stage_j(const f16* __restrict__ Wg, int j,
                                        f16* __restrict__ ring, int lane8)
{
    f16* slot = ring + (j & 3) * 1024;
    const f16* gp = Wg + j * 1024 + lane8;
    cp1k(gp, slot);
    cp1k(gp + 512, slot + 512);
}

// Consume one j: 2 ds_read_b128 frags + 4 LDS scalars -> 8 MFMA (round-robin).
__device__ __forceinline__ void consume_j(const f16* __restrict__ ring, int j,
                                          const f16* __restrict__ h0,
                                          const f16* __restrict__ h1,
                                          int lane8, int t,
                                          const f16x8 (&ip)[2][2][2],
                                          f32x16 (&acc)[2][2])
{
    const f16* slot = ring + (j & 3) * 1024;
    f16x8 w0 = *(const f16x8*)(slot + lane8);
    f16x8 w1 = *(const f16x8*)(slot + 512 + lane8);
    f16 s00 = h0[j * HSTR + t];
    f16 s01 = h0[j * HSTR + 32 + t];
    f16 s10 = h1[j * HSTR + t];
    f16 s11 = h1[j * HSTR + 32 + t];
    acc[0][0] = __builtin_amdgcn_mfma_f32_32x32x16_f16(w0, ip[0][0][0] * s00, acc[0][0], 0, 0, 0);
    acc[0][1] = __builtin_amdgcn_mfma_f32_32x32x16_f16(w0, ip[0][0][1] * s01, acc[0][1], 0, 0, 0);
    acc[1][0] = __builtin_amdgcn_mfma_f32_32x32x16_f16(w0, ip[1][0][0] * s10, acc[1][0], 0, 0, 0);
    acc[1][1] = __builtin_amdgcn_mfma_f32_32x32x16_f16(w0, ip[1][0][1] * s11, acc[1][1], 0, 0, 0);
    acc[0][0] = __builtin_amdgcn_mfma_f32_32x32x16_f16(w1, ip[0][1][0] * s00, acc[0][0], 0, 0, 0);
    acc[0][1] = __builtin_amdgcn_mfma_f32_32x32x16_f16(w1, ip[0][1][1] * s01, acc[0][1], 0, 0, 0);
    acc[1][0] = __builtin_amdgcn_mfma_f32_32x32x16_f16(w1, ip[1][1][0] * s10, acc[1][0], 0, 0, 0);
    acc[1][1] = __builtin_amdgcn_mfma_f32_32x32x16_f16(w1, ip[1][1][1] * s11, acc[1][1], 0, 0, 0);
}

// ---- h-GEMM: rows [g*32,+32), all 64 cols, TWO batches; async W ring -------
template <int HJ>
__device__ __forceinline__ void h_gemm_async(const f16* __restrict__ Wg,
                                             const f16* __restrict__ h0,
                                             const f16* __restrict__ h1,
                                             f16* __restrict__ ring,
                                             int lane8, int t,
                                             const f16x8 (&ip)[2][2][2],
                                             f32x16 (&acc)[2][2])
{
    acc[0][0] = zero16(); acc[0][1] = zero16();
    acc[1][0] = zero16(); acc[1][1] = zero16();
    WAITV(0);                                  // clean vmcnt base (drain stores)
    stage_j(Wg, 0, ring, lane8);
    stage_j(Wg, 1, ring, lane8);
    stage_j(Wg, 2, ring, lane8);
    for (int j = 0; j < HJ - 3; ++j) {
        WAITV(4);                              // j's 2 copies retired
        stage_j(Wg, j + 3, ring, lane8);
        consume_j(ring, j, h0, h1, lane8, t, ip, acc);
    }
    WAITV(4); consume_j(ring, HJ - 3, h0, h1, lane8, t, ip, acc);
    WAITV(2); consume_j(ring, HJ - 2, h0, h1, lane8, t, ip, acc);
    WAITV(0); consume_j(ring, HJ - 1, h0, h1, lane8, t, ip, acc);
}

__device__ __forceinline__ void load_bias(const float* __restrict__ bl,
                                          float (&bve)[16], int g, int q)
{
#pragma unroll
    for (int r = 0; r < 16; ++r)
        bve[r] = bl[g * 32 + (r & 3) + 8 * (r >> 2) + 4 * q];
}

__device__ __forceinline__ void epi4(const f32x16 (&acc)[2][2],
                                     f16* __restrict__ h0d, f16* __restrict__ h1d,
                                     const float (&bve)[16], int g, int t, int q)
{
#pragma unroll
    for (int r = 0; r < 16; ++r) {
        int row = g * 32 + (r & 3) + 8 * (r >> 2) + 4 * q;
        h0d[row * HSTR + t]      = (f16)(acc[0][0][r] + bve[r]);
        h0d[row * HSTR + 32 + t] = (f16)(acc[0][1][r] + bve[r]);
        h1d[row * HSTR + t]      = (f16)(acc[1][0][r] + bve[r]);
        h1d[row * HSTR + 32 + t] = (f16)(acc[1][1][r] + bve[r]);
    }
}

// =================== Kernel 1: h-chain + p-vectors =========================
__global__ void __launch_bounds__(256, 2)
cin_h(const float* __restrict__ inp, const f16* __restrict__ Wf,
      f16* __restrict__ pW,
      const float* __restrict__ b0v, const float* __restrict__ b1v)
{
    __shared__ __attribute__((aligned(16))) f16 hL[4 * 64 * HSTR];   // 36864 B
    __shared__ __attribute__((aligned(16))) f16 ringS[4][4096];      // 32768 B

    const int tid   = threadIdx.x;
    const int w     = tid >> 6;
    const int lane  = tid & 63;
    const int t     = lane & 31;
    const int q     = lane >> 5;
    const int lane8 = lane * 8;
    const int bp    = w & 1;          // batch-pair (local batches bp*2, bp*2+1)
    const int g     = w >> 1;         // row-half
    const int b0i   = blockIdx.x * 4;
    f16* ring = ringS[w];

    // Stage: 4 batches x 32 z-rows of inp (f32 coalesced) -> hL rows 0..31.
#pragma unroll
    for (int it = 0; it < 8; ++it) {
        int idx = it * 1024 + tid * 4;
        int b = idx >> 11, rem = idx & 2047;
        int z = rem >> 6, k = rem & 63;
        f32x4 v = *(const f32x4*)(inp + (size_t)(b0i + b) * 2048 + rem);
        f16x4 h4;
        h4[0] = (f16)v[0]; h4[1] = (f16)v[1]; h4[2] = (f16)v[2]; h4[3] = (f16)v[3];
        *(f16x4*)(hL + b * 64 * HSTR + z * HSTR + k) = h4;
    }
    __syncthreads();                                   // B0: h0 (=inp) ready

    // ip[b][kq][nh][i] = inp[bp*2+b][z=kq*16+q*8+i][nh*32+t]
    f16x8 ip[2][2][2];
#pragma unroll
    for (int b = 0; b < 2; ++b) {
        const f16* src = hL + (bp * 2 + b) * 64 * HSTR;
#pragma unroll
        for (int kq = 0; kq < 2; ++kq)
#pragma unroll
            for (int nh = 0; nh < 2; ++nh) {
                f16x8 v;
#pragma unroll
                for (int i = 0; i < 8; ++i)
                    v[i] = src[(kq * 16 + q * 8 + i) * HSTR + nh * 32 + t];
                ip[b][kq][nh] = v;
            }
    }
    // pB[s][i] = inp[w][z=t][k=s*16+q*8+i] — p-GEMM B-frags (wave w <-> batch w)
    f16x8 pB[4];
#pragma unroll
    for (int s = 0; s < 4; ++s)
        pB[s] = *(const f16x8*)(hL + w * 64 * HSTR + t * HSTR + s * 16 + q * 8);

    f16* pMy = pW + (size_t)(b0i + w) * PBS;
    const f16* H0 = Wf;
    const f16* H1 = Wf + 131072;
    f16* hA = hL + (bp * 2) * 64 * HSTR;
    f16* hB = hL + (bp * 2 + 1) * 64 * HSTR;
    f32x16 acc[2][2];
    float bve[16];

    // ---- Layer 0 (HJ=32) ----
    p_chunk(hL + w * 64 * HSTR, pB, pMy, t, q);        // p0: wave w, batch w
    h_gemm_async<32>(H0 + g * 64 * 512, hA, hB, ring, lane8, t, ip, acc);
    load_bias(b0v, bve, g, q);
    __syncthreads();                                   // B1: all h0 reads done
    epi4(acc, hA, hB, bve, g, t, q);                   // h1 (rows 0..63)
    __syncthreads();                                   // B2: h1 ready

    // ---- Layer 1 (HJ=64) ----
    p_chunk(hL + w * 64 * HSTR,             pB, pMy + 1024, t, q);
    p_chunk(hL + w * 64 * HSTR + 32 * HSTR, pB, pMy + 2048, t, q);
    h_gemm_async<64>(H1 + g * 128 * 512, hA, hB, ring, lane8, t, ip, acc);
    load_bias(b1v, bve, g, q);
    __syncthreads();                                   // B3: all h1 reads done
    epi4(acc, hA, hB, bve, g, t, q);                   // h1 -> h2 in place
    __syncthreads();                                   // B4: h2 ready

    p_chunk(hL + w * 64 * HSTR,             pB, pMy + 3072, t, q);
    p_chunk(hL + w * 64 * HSTR + 32 * HSTR, pB, pMy + 4096, t, q);
}

// =================== Kernel 2: out GEMMs (N = batch) =======================
// Block = (32-batch group) x (one M=32 tile).  4 waves = 4 K-quarters.
template <int KK>
__device__ __forceinline__ void o_tile32(const f16* __restrict__ Om,  // m-tile frag base
                                         const f16* __restrict__ pBase,
                                         const float* __restrict__ biasp,
                                         float* __restrict__ out,
                                         float* __restrict__ rP,
                                         int bg, int colbase, int tid)
{
    constexpr int S = KK / 4;
    const int w = tid >> 6, lane = tid & 63, t = lane & 31, q = lane >> 5;
    const int lane8 = lane * 8;
    const f16* Ap = Om + (size_t)(w * S) * 512 + lane8;
    const f16* Bp = pBase + (size_t)(bg * 32 + t) * PBS + w * S * 16 + q * 8;

    f32x16 acc = zero16();
    f16x8 af[8], bf[8];
#pragma unroll
    for (int i = 0; i < 8; ++i) {
        af[i] = *(const f16x8*)(Ap + i * 512);
        bf[i] = *(const f16x8*)(Bp + i * 16);
    }
#pragma unroll 8
    for (int s = 0; s < S; ++s) {
        int idx = s & 7;
        f16x8 a = af[idx], b = bf[idx];
        int sn = s + 8 < S ? s + 8 : S - 1;            // clamped refill
        af[idx] = *(const f16x8*)(Ap + sn * 512);
        bf[idx] = *(const f16x8*)(Bp + sn * 16);
        acc = __builtin_amdgcn_mfma_f32_32x32x16_f16(a, b, acc, 0, 0, 0);
    }
#pragma unroll
    for (int r = 0; r < 16; ++r) {
        int m = (r & 3) + 8 * (r >> 2) + 4 * q;
        rP[(w * 32 + t) * 32 + m] = acc[r];
    }
    __syncthreads();
    {
        int n  = tid >> 3;                             // batch row 0..31
        int o4 = (tid & 7) * 4;                        // col 0..31 step 4
        f32x4 v0 = *(const f32x4*)(rP + (0 * 32 + n) * 32 + o4);
        f32x4 v1 = *(const f32x4*)(rP + (1 * 32 + n) * 32 + o4);
        f32x4 v2 = *(const f32x4*)(rP + (2 * 32 + n) * 32 + o4);
        f32x4 v3 = *(const f32x4*)(rP + (3 * 32 + n) * 32 + o4);
        f32x4 bb = *(const f32x4*)(biasp + o4);
        f32x4 ov;
        ov[0] = v0[0] + v1[0] + v2[0] + v3[0] + 64.0f * bb[0];
        ov[1] = v0[1] + v1[1] + v2[1] + v3[1] + 64.0f * bb[1];
        ov[2] = v0[2] + v1[2] + v2[2] + v3[2] + 64.0f * bb[2];
        ov[3] = v0[3] + v1[3] + v2[3] + v3[3] + 64.0f * bb[3];
        *(f32x4*)(out + (size_t)(bg * 32 + n) * 256 + colbase + o4) = ov;
    }
}

__global__ void __launch_bounds__(256, 2)
cin_out(const f16* __restrict__ Wf, const f16* __restrict__ pW,
        const float* __restrict__ b0v, const float* __restrict__ b1v,
        const float* __restrict__ b2v, float* __restrict__ out)
{
    __shared__ __attribute__((aligned(16))) float rP[4 * 32 * 32];  // 16 KB
    const int tid = threadIdx.x;
    const int r  = blockIdx.x & 7;      // m-tile id (8 total)
    const int bg = blockIdx.x >> 3;     // 32-batch group (64 of them)
    if (r < 2)        // O0: W0 rows 64..127, KK=64, out cols 0..63
        o_tile32<64>(Wf + 65536 + r * 64 * 512, pW, b0v + 64 + r * 32,
                     out, rP, bg, r * 32, tid);
    else if (r < 4)   // O1: W1 rows 64..127, KK=128, out cols 64..127
        o_tile32<128>(Wf + 262144 + (r - 2) * 128 * 512, pW + 1024,
                      b1v + 64 + (r - 2) * 32, out, rP, bg, 64 + (r - 2) * 32, tid);
    else              // O2: W2 all 128 rows, KK=128, out cols 128..255
        o_tile32<128>(Wf + 393216 + (r - 4) * 128 * 512, pW + 3072,
                      b2v + (r - 4) * 32, out, rP, bg, 128 + (r - 4) * 32, tid);
}

extern "C" void kernel_launch(void* const* d_in, const int* in_sizes, int n_in,
                              void* d_out, int out_size, void* d_ws, size_t ws_size,
                              hipStream_t stream)
{
    const float* inp = (const float*)d_in[0];
    const float* W0  = (const float*)d_in[1];
    const float* b0  = (const float*)d_in[2];
    const float* W1  = (const float*)d_in[3];
    const float* b1  = (const float*)d_in[4];
    const float* W2  = (const float*)d_in[5];
    const float* b2  = (const float*)d_in[6];
    float* out = (float*)d_out;

    f16* Wf = (f16*)d_ws;             // 655360 f16 = 1.25 MB fragment-ordered
    f16* pW = Wf + 655360;            // 2048 * 5120 f16 = 20 MB p-vectors

    prep_frag<<<320, 256, 0, stream>>>(W0, W1, W2, Wf);
    cin_h<<<512, 256, 0, stream>>>(inp, Wf, pW, b0, b1);
    cin_out<<<512, 256, 0, stream>>>(Wf, pW, b0, b1, b2, out);
}